// Round 1
// baseline (246.499 us; speedup 1.0000x reference)
//
#include <hip/hip_runtime.h>
#include <hip/hip_bf16.h>

typedef unsigned short u16;
typedef __attribute__((ext_vector_type(8))) short short8;
typedef __attribute__((ext_vector_type(8))) __bf16 bf16x8;
typedef __attribute__((ext_vector_type(4))) float f32x4;

#define DEV static __device__ __forceinline__

DEV float bf2f(u16 u) { unsigned v = ((unsigned)u) << 16; float f; __builtin_memcpy(&f, &v, 4); return f; }
DEV u16 f2bf(float f) {
  unsigned u; __builtin_memcpy(&u, &f, 4);
  unsigned lsb = (u >> 16) & 1;
  u += 0x7fffu + lsb;  // round to nearest even
  return (u16)(u >> 16);
}
DEV f32x4 mfma16(short8 a, short8 b, f32x4 c) {
  return __builtin_amdgcn_mfma_f32_16x16x32_bf16(
      __builtin_bit_cast(bf16x8, a), __builtin_bit_cast(bf16x8, b), c, 0, 0, 0);
}
DEV short8 ld8(const u16* p) { return *(const short8*)p; }

// ---------------- prep: head_w (H,D,3DH) -> W_T[(h*192+e)*512 + d] hi/lo ----------------
__global__ void prep_qkv(const float* __restrict__ hw, u16* __restrict__ hi, u16* __restrict__ lo) {
  int idx = blockIdx.x * 256 + threadIdx.x;
  if (idx >= 8 * 512 * 192) return;
  int e = idx % 192;
  int d = (idx / 192) % 512;
  int h = idx / (192 * 512);
  float v = hw[idx];
  size_t oi = (size_t)(h * 192 + e) * 512 + d;
  u16 hh = f2bf(v);
  hi[oi] = hh;
  lo[oi] = f2bf(v - bf2f(hh));
}

// ---------------- prep: W (K,N) row-major -> W_T (N,K) bf16 ----------------
__global__ void prep_T(const float* __restrict__ w, u16* __restrict__ out, int K, int N) {
  int idx = blockIdx.x * 256 + threadIdx.x;
  if (idx >= K * N) return;
  int n = idx % N, k = idx / N;
  out[(size_t)n * K + k] = f2bf(w[idx]);
}

// ---------------- LayerNorm: f32 (rows x 512) -> bf16 hi/lo ----------------
__global__ __launch_bounds__(256) void ln_kernel(const float* __restrict__ in,
                                                 const float* __restrict__ w,
                                                 const float* __restrict__ bb,
                                                 u16* __restrict__ hi, u16* __restrict__ lo) {
  const int wv = threadIdx.x >> 6, lane = threadIdx.x & 63;
  const int row = blockIdx.x * 4 + wv;
  const float4* r = (const float4*)(in + (size_t)row * 512);
  float4 a0 = r[lane * 2], a1 = r[lane * 2 + 1];
  float s = a0.x + a0.y + a0.z + a0.w + a1.x + a1.y + a1.z + a1.w;
  float ss = a0.x * a0.x + a0.y * a0.y + a0.z * a0.z + a0.w * a0.w +
             a1.x * a1.x + a1.y * a1.y + a1.z * a1.z + a1.w * a1.w;
#pragma unroll
  for (int m = 1; m < 64; m <<= 1) { s += __shfl_xor(s, m); ss += __shfl_xor(ss, m); }
  float mu = s * (1.f / 512.f);
  float var = ss * (1.f / 512.f) - mu * mu;
  float rstd = rsqrtf(var + 1e-5f);
  const float4* wp = (const float4*)w + lane * 2;
  const float4* bp = (const float4*)bb + lane * 2;
  float4 w0 = wp[0], w1v = wp[1], b0 = bp[0], b1v = bp[1];
  float xv[8] = {a0.x, a0.y, a0.z, a0.w, a1.x, a1.y, a1.z, a1.w};
  float wv8[8] = {w0.x, w0.y, w0.z, w0.w, w1v.x, w1v.y, w1v.z, w1v.w};
  float bv8[8] = {b0.x, b0.y, b0.z, b0.w, b1v.x, b1v.y, b1v.z, b1v.w};
  short8 oh, ol;
#pragma unroll
  for (int i = 0; i < 8; i++) {
    float v = (xv[i] - mu) * rstd * wv8[i] + bv8[i];
    u16 hh = f2bf(v);
    oh[i] = (short)hh;
    ol[i] = (short)f2bf(v - bf2f(hh));
  }
  *(short8*)(hi + (size_t)row * 512 + lane * 8) = oh;
  *(short8*)(lo + (size_t)row * 512 + lane * 8) = ol;
}

// ---------------- GEMM: C(MxN) = A(MxK) @ BT(NxK)^T, bf16 MFMA, optional split ----------------
// EPI: 0 = store bf16; 1 = +res, store f32; 2 = +bias, store bf16; 3 = +bias, gelu, +res, f32
//      4 = split store (hi->outb, lo->outb2)
template <bool SPLIT, int EPI>
__global__ __launch_bounds__(256) void gemm_bf16(const u16* __restrict__ A, const u16* __restrict__ Al,
                                                 const u16* __restrict__ BT, const u16* __restrict__ BTl,
                                                 const float* __restrict__ res, const float* __restrict__ bias,
                                                 u16* __restrict__ outb, u16* __restrict__ outb2,
                                                 float* __restrict__ outf, int M, int N, int K) {
  __shared__ __align__(16) u16 As[128][40];
  __shared__ __align__(16) u16 Bs[128][40];
  __shared__ __align__(16) u16 Asl[SPLIT ? 128 : 1][40];
  __shared__ __align__(16) u16 Bsl[SPLIT ? 128 : 1][40];
  const int tid = threadIdx.x;
  const int lane = tid & 63, wv = tid >> 6;
  const int wm = wv >> 1, wn = wv & 1;
  const int g = lane >> 4, r16 = lane & 15;
  const int bm = blockIdx.x * 128, bn = blockIdx.y * 128;
  const int arow = tid >> 1, acol = (tid & 1) * 16;
  f32x4 acc[4][4] = {};
  for (int kt = 0; kt < K; kt += 32) {
    const u16* ga = A + (size_t)(bm + arow) * K + kt + acol;
    const u16* gb = BT + (size_t)(bn + arow) * K + kt + acol;
    short8 va0 = ld8(ga), va1 = ld8(ga + 8);
    short8 vb0 = ld8(gb), vb1 = ld8(gb + 8);
    short8 wa0, wa1, wb0, wb1;
    if (SPLIT) {
      const u16* ga2 = Al + (size_t)(bm + arow) * K + kt + acol;
      const u16* gb2 = BTl + (size_t)(bn + arow) * K + kt + acol;
      wa0 = ld8(ga2); wa1 = ld8(ga2 + 8);
      wb0 = ld8(gb2); wb1 = ld8(gb2 + 8);
    }
    __syncthreads();
    *(short8*)&As[arow][acol] = va0; *(short8*)&As[arow][acol + 8] = va1;
    *(short8*)&Bs[arow][acol] = vb0; *(short8*)&Bs[arow][acol + 8] = vb1;
    if (SPLIT) {
      *(short8*)&Asl[arow][acol] = wa0; *(short8*)&Asl[arow][acol + 8] = wa1;
      *(short8*)&Bsl[arow][acol] = wb0; *(short8*)&Bsl[arow][acol + 8] = wb1;
    }
    __syncthreads();
    short8 af[4], bf_[4], afl[4], bfl[4];
#pragma unroll
    for (int mi = 0; mi < 4; mi++) af[mi] = *(const short8*)&As[wm * 64 + mi * 16 + r16][g * 8];
#pragma unroll
    for (int ni = 0; ni < 4; ni++) bf_[ni] = *(const short8*)&Bs[wn * 64 + ni * 16 + r16][g * 8];
    if (SPLIT) {
#pragma unroll
      for (int mi = 0; mi < 4; mi++) afl[mi] = *(const short8*)&Asl[wm * 64 + mi * 16 + r16][g * 8];
#pragma unroll
      for (int ni = 0; ni < 4; ni++) bfl[ni] = *(const short8*)&Bsl[wn * 64 + ni * 16 + r16][g * 8];
    }
#pragma unroll
    for (int mi = 0; mi < 4; mi++)
#pragma unroll
      for (int ni = 0; ni < 4; ni++) {
        acc[mi][ni] = mfma16(af[mi], bf_[ni], acc[mi][ni]);
        if (SPLIT) {
          acc[mi][ni] = mfma16(af[mi], bfl[ni], acc[mi][ni]);
          acc[mi][ni] = mfma16(afl[mi], bf_[ni], acc[mi][ni]);
        }
      }
  }
#pragma unroll
  for (int mi = 0; mi < 4; mi++)
#pragma unroll
    for (int ni = 0; ni < 4; ni++) {
      int col = bn + wn * 64 + ni * 16 + r16;
      int row0 = bm + wm * 64 + mi * 16 + g * 4;
#pragma unroll
      for (int j = 0; j < 4; j++) {
        size_t oi = (size_t)(row0 + j) * N + col;
        float v = acc[mi][ni][j];
        if (EPI == 0) {
          outb[oi] = f2bf(v);
        } else if (EPI == 4) {
          u16 hh = f2bf(v);
          outb[oi] = hh;
          outb2[oi] = f2bf(v - bf2f(hh));
        } else if (EPI == 1) {
          outf[oi] = v + res[oi];
        } else if (EPI == 2) {
          outb[oi] = f2bf(v + bias[col]);
        } else {
          float u = v + bias[col];
          float gl = 0.5f * u * (1.0f + erff(u * 0.70710678118f));
          outf[oi] = gl + res[oi];
        }
      }
    }
}

// ---------------- flash attention: qkv (4096 x 1536) hi/lo -> o (4096 x 512) bf16 ----------------
__global__ __launch_bounds__(256) void attn_kernel(const u16* __restrict__ qkv_hi,
                                                   const u16* __restrict__ qkv_lo,
                                                   u16* __restrict__ o) {
  constexpr int SK = 72, SV = 40, SP = 36;
  __shared__ __align__(16) u16 Kh[32 * SK], Kl[32 * SK], Vt[64 * SV];
  __shared__ __align__(16) float Pl[4][16 * SP];
  const int tid = threadIdx.x, lane = tid & 63, wv = tid >> 6;
  const int g = lane >> 4, r16 = lane & 15;
  const int qb = blockIdx.x * 128;
  const int b = blockIdx.y >> 3, h = blockIdx.y & 7;
  const size_t base = ((size_t)b * 2048) * 1536 + (size_t)h * 192;
  const u16* Qh = qkv_hi + base;
  const u16* Ql = qkv_lo + base;
  const u16* Kgh = qkv_hi + base + 64;
  const u16* Kgl = qkv_lo + base + 64;
  const u16* Vg = qkv_hi + base + 128;

  short8 qh[2][2], qlo[2][2];
#pragma unroll
  for (int t = 0; t < 2; t++)
#pragma unroll
    for (int ks = 0; ks < 2; ks++) {
      int row = qb + wv * 32 + t * 16 + r16;
      qh[t][ks] = ld8(Qh + (size_t)row * 1536 + ks * 32 + g * 8);
      qlo[t][ks] = ld8(Ql + (size_t)row * 1536 + ks * 32 + g * 8);
    }
  f32x4 oacc[2][4] = {};
  float mrow[2][4], lrow[2][4];
#pragma unroll
  for (int t = 0; t < 2; t++)
#pragma unroll
    for (int j = 0; j < 4; j++) { mrow[t][j] = -3e38f; lrow[t][j] = 0.f; }

  const int srow = tid >> 3, scol = (tid & 7) * 8;
  for (int kt = 0; kt < 2048; kt += 32) {
    short8 k0 = ld8(Kgh + (size_t)(kt + srow) * 1536 + scol);
    short8 k1 = ld8(Kgl + (size_t)(kt + srow) * 1536 + scol);
    short8 vv = ld8(Vg + (size_t)(kt + srow) * 1536 + scol);
    __syncthreads();
    *(short8*)&Kh[srow * SK + scol] = k0;
    *(short8*)&Kl[srow * SK + scol] = k1;
#pragma unroll
    for (int i = 0; i < 8; i++) Vt[(scol + i) * SV + srow] = (u16)vv[i];
    __syncthreads();
#pragma unroll
    for (int t = 0; t < 2; t++) {
      f32x4 s0 = {0.f, 0.f, 0.f, 0.f}, s1 = {0.f, 0.f, 0.f, 0.f};
#pragma unroll
      for (int ks = 0; ks < 2; ks++) {
        short8 bh0 = *(const short8*)&Kh[r16 * SK + ks * 32 + g * 8];
        short8 bl0 = *(const short8*)&Kl[r16 * SK + ks * 32 + g * 8];
        s0 = mfma16(qh[t][ks], bh0, s0);
        s0 = mfma16(qh[t][ks], bl0, s0);
        s0 = mfma16(qlo[t][ks], bh0, s0);
        short8 bh1 = *(const short8*)&Kh[(16 + r16) * SK + ks * 32 + g * 8];
        short8 bl1 = *(const short8*)&Kl[(16 + r16) * SK + ks * 32 + g * 8];
        s1 = mfma16(qh[t][ks], bh1, s1);
        s1 = mfma16(qh[t][ks], bl1, s1);
        s1 = mfma16(qlo[t][ks], bh1, s1);
      }
      float al[4];
#pragma unroll
      for (int j = 0; j < 4; j++) {
        float a = s0[j] * 0.125f, c = s1[j] * 0.125f;
        float tm = fmaxf(a, c);
        tm = fmaxf(tm, __shfl_xor(tm, 1));
        tm = fmaxf(tm, __shfl_xor(tm, 2));
        tm = fmaxf(tm, __shfl_xor(tm, 4));
        tm = fmaxf(tm, __shfl_xor(tm, 8));
        float mn = fmaxf(mrow[t][j], tm);
        float e0 = __expf(a - mn), e1 = __expf(c - mn);
        al[j] = __expf(mrow[t][j] - mn);
        mrow[t][j] = mn;
        float rs = e0 + e1;
        rs += __shfl_xor(rs, 1);
        rs += __shfl_xor(rs, 2);
        rs += __shfl_xor(rs, 4);
        rs += __shfl_xor(rs, 8);
        lrow[t][j] = lrow[t][j] * al[j] + rs;
        Pl[wv][(g * 4 + j) * SP + r16] = e0;
        Pl[wv][(g * 4 + j) * SP + 16 + r16] = e1;
      }
#pragma unroll
      for (int dt = 0; dt < 4; dt++)
#pragma unroll
        for (int j = 0; j < 4; j++) oacc[t][dt][j] *= al[j];
      f32x4 pf0 = *(const f32x4*)&Pl[wv][r16 * SP + g * 8];
      f32x4 pf1 = *(const f32x4*)&Pl[wv][r16 * SP + g * 8 + 4];
      short8 pa;
#pragma unroll
      for (int i = 0; i < 4; i++) {
        pa[i] = (short)f2bf(pf0[i]);
        pa[i + 4] = (short)f2bf(pf1[i]);
      }
#pragma unroll
      for (int dt = 0; dt < 4; dt++) {
        short8 vb = *(const short8*)&Vt[(dt * 16 + r16) * SV + g * 8];
        oacc[t][dt] = mfma16(pa, vb, oacc[t][dt]);
      }
    }
  }
#pragma unroll
  for (int t = 0; t < 2; t++)
#pragma unroll
    for (int dt = 0; dt < 4; dt++)
#pragma unroll
      for (int j = 0; j < 4; j++) {
        int row = b * 2048 + qb + wv * 32 + t * 16 + g * 4 + j;
        int col = h * 64 + dt * 16 + r16;
        o[(size_t)row * 512 + col] = f2bf(oacc[t][dt][j] / lrow[t][j]);
      }
}

// ---------------- launcher ----------------
extern "C" void kernel_launch(void* const* d_in, const int* in_sizes, int n_in,
                              void* d_out, int out_size, void* d_ws, size_t ws_size,
                              hipStream_t stream) {
  const float* z = (const float*)d_in[0];
  const float* head_w = (const float*)d_in[1];
  const float* w_o = (const float*)d_in[2];
  const float* ln_w = (const float*)d_in[3];
  const float* ln_b = (const float*)d_in[4];
  const float* w1 = (const float*)d_in[5];
  const float* b1 = (const float*)d_in[6];
  const float* w2 = (const float*)d_in[7];
  const float* b2 = (const float*)d_in[8];
  float* out = (float*)d_out;

  size_t off = 0;
  auto alc = [&](size_t n) {
    void* p = (char*)d_ws + off;
    off += (n + 255) & ~(size_t)255;
    return p;
  };
  u16* x_hi = (u16*)alc((size_t)4096 * 512 * 2);
  u16* x_lo = (u16*)alc((size_t)4096 * 512 * 2);
  u16* wqh = (u16*)alc((size_t)1536 * 512 * 2);
  u16* wql = (u16*)alc((size_t)1536 * 512 * 2);
  u16* woT = (u16*)alc((size_t)512 * 512 * 2);
  u16* w1T = (u16*)alc((size_t)128 * 512 * 2);
  u16* w2T = (u16*)alc((size_t)512 * 128 * 2);
  u16* qkvh = (u16*)alc((size_t)4096 * 1536 * 2);
  u16* qkvl = (u16*)alc((size_t)4096 * 1536 * 2);
  u16* ob = (u16*)alc((size_t)4096 * 512 * 2);
  float* z2 = (float*)alc((size_t)4096 * 512 * 4);
  u16* tb = (u16*)alc((size_t)4096 * 128 * 2);

  // weight prep
  prep_qkv<<<(8 * 512 * 192 + 255) / 256, 256, 0, stream>>>(head_w, wqh, wql);
  prep_T<<<(512 * 512 + 255) / 256, 256, 0, stream>>>(w_o, woT, 512, 512);
  prep_T<<<(512 * 128 + 255) / 256, 256, 0, stream>>>(w1, w1T, 512, 128);
  prep_T<<<(128 * 512 + 255) / 256, 256, 0, stream>>>(w2, w2T, 128, 512);

  // LN1: z -> x hi/lo
  ln_kernel<<<1024, 256, 0, stream>>>(z, ln_w, ln_b, x_hi, x_lo);

  // QKV projection (split for precision): qkv = x @ Wqkv
  gemm_bf16<true, 4><<<dim3(32, 12), 256, 0, stream>>>(x_hi, x_lo, wqh, wql, nullptr, nullptr,
                                                       qkvh, qkvl, nullptr, 4096, 1536, 512);

  // flash attention
  attn_kernel<<<dim3(16, 16), 256, 0, stream>>>(qkvh, qkvl, ob);

  // z2 = o @ w_o + z
  gemm_bf16<false, 1><<<dim3(32, 4), 256, 0, stream>>>(ob, nullptr, woT, nullptr, z, nullptr,
                                                       nullptr, nullptr, z2, 4096, 512, 512);

  // LN2: z2 -> y hi/lo (reuse x buffers)
  ln_kernel<<<1024, 256, 0, stream>>>(z2, ln_w, ln_b, x_hi, x_lo);

  // t = y @ w1 + b1
  gemm_bf16<false, 2><<<dim3(32, 1), 256, 0, stream>>>(x_hi, nullptr, w1T, nullptr, nullptr, b1,
                                                       tb, nullptr, nullptr, 4096, 128, 512);

  // out = gelu(t @ w2 + b2) + z2
  gemm_bf16<false, 3><<<dim3(32, 4), 256, 0, stream>>>(tb, nullptr, w2T, nullptr, z2, b2,
                                                       nullptr, nullptr, out, 4096, 512, 128);
}

// Round 2
// 196.374 us; speedup vs baseline: 1.2552x; 1.2552x over previous
//
#include <hip/hip_runtime.h>
#include <hip/hip_bf16.h>

typedef unsigned short u16;
typedef __attribute__((ext_vector_type(8))) short short8;
typedef __attribute__((ext_vector_type(8))) __bf16 bf16x8;
typedef __attribute__((ext_vector_type(4))) float f32x4;

#define DEV static __device__ __forceinline__

DEV float bf2f(u16 u) { unsigned v = ((unsigned)u) << 16; float f; __builtin_memcpy(&f, &v, 4); return f; }
DEV u16 f2bf(float f) {
  unsigned u; __builtin_memcpy(&u, &f, 4);
  unsigned lsb = (u >> 16) & 1;
  u += 0x7fffu + lsb;  // round to nearest even
  return (u16)(u >> 16);
}
DEV f32x4 mfma16(short8 a, short8 b, f32x4 c) {
  return __builtin_amdgcn_mfma_f32_16x16x32_bf16(
      __builtin_bit_cast(bf16x8, a), __builtin_bit_cast(bf16x8, b), c, 0, 0, 0);
}
DEV short8 ld8(const u16* p) { return *(const short8*)p; }

// ---------------- fused weight prep ----------------
// qkv: head_w (H,D,3DH) -> W_T[(h*192+e)*512 + d] hi/lo (split bf16)
// wo (512,512)->woT(512,512); w1 (512,128)->w1T(128,512); w2 (128,512)->w2T(512,128)
__global__ void prep_all(const float* __restrict__ hw, const float* __restrict__ wo,
                         const float* __restrict__ w1, const float* __restrict__ w2,
                         u16* __restrict__ wqh, u16* __restrict__ wql,
                         u16* __restrict__ woT, u16* __restrict__ w1T, u16* __restrict__ w2T) {
  int idx = blockIdx.x * 256 + threadIdx.x;
  if (idx < 786432) {  // 8*512*192
    int e = idx % 192;
    int d = (idx / 192) % 512;
    int h = idx / (192 * 512);
    float v = hw[idx];
    size_t oi = (size_t)(h * 192 + e) * 512 + d;
    u16 hh = f2bf(v);
    wqh[oi] = hh;
    wql[oi] = f2bf(v - bf2f(hh));
  } else if (idx < 786432 + 262144) {
    int i = idx - 786432;  // wo: K=512, N=512
    int n = i % 512, k = i / 512;
    woT[(size_t)n * 512 + k] = f2bf(wo[i]);
  } else if (idx < 786432 + 262144 + 65536) {
    int i = idx - (786432 + 262144);  // w1: K=512, N=128
    int n = i % 128, k = i / 128;
    w1T[(size_t)n * 512 + k] = f2bf(w1[i]);
  } else if (idx < 786432 + 262144 + 131072) {
    int i = idx - (786432 + 262144 + 65536);  // w2: K=128, N=512
    int n = i % 512, k = i / 512;
    w2T[(size_t)n * 128 + k] = f2bf(w2[i]);
  }
}

// ---------------- LayerNorm: f32 (rows x 512) -> bf16 hi/lo ----------------
__global__ __launch_bounds__(256) void ln_kernel(const float* __restrict__ in,
                                                 const float* __restrict__ w,
                                                 const float* __restrict__ bb,
                                                 u16* __restrict__ hi, u16* __restrict__ lo) {
  const int wv = threadIdx.x >> 6, lane = threadIdx.x & 63;
  const int row = blockIdx.x * 4 + wv;
  const float4* r = (const float4*)(in + (size_t)row * 512);
  float4 a0 = r[lane * 2], a1 = r[lane * 2 + 1];
  float s = a0.x + a0.y + a0.z + a0.w + a1.x + a1.y + a1.z + a1.w;
  float ss = a0.x * a0.x + a0.y * a0.y + a0.z * a0.z + a0.w * a0.w +
             a1.x * a1.x + a1.y * a1.y + a1.z * a1.z + a1.w * a1.w;
#pragma unroll
  for (int m = 1; m < 64; m <<= 1) { s += __shfl_xor(s, m); ss += __shfl_xor(ss, m); }
  float mu = s * (1.f / 512.f);
  float var = ss * (1.f / 512.f) - mu * mu;
  float rstd = rsqrtf(var + 1e-5f);
  const float4* wp = (const float4*)w + lane * 2;
  const float4* bp = (const float4*)bb + lane * 2;
  float4 w0 = wp[0], w1v = wp[1], b0 = bp[0], b1v = bp[1];
  float xv[8] = {a0.x, a0.y, a0.z, a0.w, a1.x, a1.y, a1.z, a1.w};
  float wv8[8] = {w0.x, w0.y, w0.z, w0.w, w1v.x, w1v.y, w1v.z, w1v.w};
  float bv8[8] = {b0.x, b0.y, b0.z, b0.w, b1v.x, b1v.y, b1v.z, b1v.w};
  short8 oh, ol;
#pragma unroll
  for (int i = 0; i < 8; i++) {
    float v = (xv[i] - mu) * rstd * wv8[i] + bv8[i];
    u16 hh = f2bf(v);
    oh[i] = (short)hh;
    ol[i] = (short)f2bf(v - bf2f(hh));
  }
  *(short8*)(hi + (size_t)row * 512 + lane * 8) = oh;
  *(short8*)(lo + (size_t)row * 512 + lane * 8) = ol;
}

// ---------------- GEMM: C(MxN) = A(MxK) @ BT(NxK)^T, bf16 MFMA, optional split ----------------
template <bool SPLIT, int EPI>
__global__ __launch_bounds__(256) void gemm_bf16(const u16* __restrict__ A, const u16* __restrict__ Al,
                                                 const u16* __restrict__ BT, const u16* __restrict__ BTl,
                                                 const float* __restrict__ res, const float* __restrict__ bias,
                                                 u16* __restrict__ outb, u16* __restrict__ outb2,
                                                 float* __restrict__ outf, int M, int N, int K) {
  __shared__ __align__(16) u16 As[128][40];
  __shared__ __align__(16) u16 Bs[128][40];
  __shared__ __align__(16) u16 Asl[SPLIT ? 128 : 1][40];
  __shared__ __align__(16) u16 Bsl[SPLIT ? 128 : 1][40];
  const int tid = threadIdx.x;
  const int lane = tid & 63, wv = tid >> 6;
  const int wm = wv >> 1, wn = wv & 1;
  const int g = lane >> 4, r16 = lane & 15;
  const int bm = blockIdx.x * 128, bn = blockIdx.y * 128;
  const int arow = tid >> 1, acol = (tid & 1) * 16;
  f32x4 acc[4][4] = {};
  for (int kt = 0; kt < K; kt += 32) {
    const u16* ga = A + (size_t)(bm + arow) * K + kt + acol;
    const u16* gb = BT + (size_t)(bn + arow) * K + kt + acol;
    short8 va0 = ld8(ga), va1 = ld8(ga + 8);
    short8 vb0 = ld8(gb), vb1 = ld8(gb + 8);
    short8 wa0, wa1, wb0, wb1;
    if (SPLIT) {
      const u16* ga2 = Al + (size_t)(bm + arow) * K + kt + acol;
      const u16* gb2 = BTl + (size_t)(bn + arow) * K + kt + acol;
      wa0 = ld8(ga2); wa1 = ld8(ga2 + 8);
      wb0 = ld8(gb2); wb1 = ld8(gb2 + 8);
    }
    __syncthreads();
    *(short8*)&As[arow][acol] = va0; *(short8*)&As[arow][acol + 8] = va1;
    *(short8*)&Bs[arow][acol] = vb0; *(short8*)&Bs[arow][acol + 8] = vb1;
    if (SPLIT) {
      *(short8*)&Asl[arow][acol] = wa0; *(short8*)&Asl[arow][acol + 8] = wa1;
      *(short8*)&Bsl[arow][acol] = wb0; *(short8*)&Bsl[arow][acol + 8] = wb1;
    }
    __syncthreads();
    short8 af[4], bf_[4], afl[4], bfl[4];
#pragma unroll
    for (int mi = 0; mi < 4; mi++) af[mi] = *(const short8*)&As[wm * 64 + mi * 16 + r16][g * 8];
#pragma unroll
    for (int ni = 0; ni < 4; ni++) bf_[ni] = *(const short8*)&Bs[wn * 64 + ni * 16 + r16][g * 8];
    if (SPLIT) {
#pragma unroll
      for (int mi = 0; mi < 4; mi++) afl[mi] = *(const short8*)&Asl[wm * 64 + mi * 16 + r16][g * 8];
#pragma unroll
      for (int ni = 0; ni < 4; ni++) bfl[ni] = *(const short8*)&Bsl[wn * 64 + ni * 16 + r16][g * 8];
    }
#pragma unroll
    for (int mi = 0; mi < 4; mi++)
#pragma unroll
      for (int ni = 0; ni < 4; ni++) {
        acc[mi][ni] = mfma16(af[mi], bf_[ni], acc[mi][ni]);
        if (SPLIT) {
          acc[mi][ni] = mfma16(af[mi], bfl[ni], acc[mi][ni]);
          acc[mi][ni] = mfma16(afl[mi], bf_[ni], acc[mi][ni]);
        }
      }
  }
#pragma unroll
  for (int mi = 0; mi < 4; mi++)
#pragma unroll
    for (int ni = 0; ni < 4; ni++) {
      int col = bn + wn * 64 + ni * 16 + r16;
      int row0 = bm + wm * 64 + mi * 16 + g * 4;
#pragma unroll
      for (int j = 0; j < 4; j++) {
        size_t oi = (size_t)(row0 + j) * N + col;
        float v = acc[mi][ni][j];
        if (EPI == 0) {
          outb[oi] = f2bf(v);
        } else if (EPI == 4) {
          u16 hh = f2bf(v);
          outb[oi] = hh;
          outb2[oi] = f2bf(v - bf2f(hh));
        } else if (EPI == 1) {
          outf[oi] = v + res[oi];
        } else if (EPI == 2) {
          outb[oi] = f2bf(v + bias[col]);
        } else {
          float u = v + bias[col];
          float gl = 0.5f * u * (1.0f + erff(u * 0.70710678118f));
          outf[oi] = gl + res[oi];
        }
      }
    }
}

// ---------------- flash attention v2: QBLK=64 (4 waves x 16 rows), KVBLK=64 ----------------
// grid (32, 16); conflict-free LDS maps; software-pipelined staging loads.
__global__ __launch_bounds__(256) void attn_kernel(const u16* __restrict__ qkv_hi,
                                                   const u16* __restrict__ qkv_lo,
                                                   u16* __restrict__ o) {
  constexpr int SK = 72;  // u16 stride (144B = 9 x 16B -> odd slot spread)
  constexpr int SV = 72;
  constexpr int SP = 68;  // f32 stride (272B = 17 x 16B)
  __shared__ __align__(16) u16 Kh[64 * SK], Kl[64 * SK], Vt[64 * SV];
  __shared__ __align__(16) float Pl[4][16 * SP];
  const int tid = threadIdx.x, lane = tid & 63, w = tid >> 6;
  const int g = lane >> 4, r16 = lane & 15;
  const int qb = blockIdx.x * 64;
  const int b = blockIdx.y >> 3, h = blockIdx.y & 7;
  const size_t base = (size_t)b * 2048 * 1536 + (size_t)h * 192;
  const u16* Qh = qkv_hi + base;
  const u16* Ql = qkv_lo + base;
  const u16* KgH = qkv_hi + base + 64;
  const u16* KgL = qkv_lo + base + 64;
  const u16* Vg = qkv_hi + base + 128;

  // Q A-fragments (row = r16 of this wave's 16 rows, k = ks*32 + g*8 + i)
  const int qrow = qb + w * 16 + r16;
  short8 qh[2], qlo[2];
#pragma unroll
  for (int ks = 0; ks < 2; ks++) {
    qh[ks] = ld8(Qh + (size_t)qrow * 1536 + ks * 32 + g * 8);
    qlo[ks] = ld8(Ql + (size_t)qrow * 1536 + ks * 32 + g * 8);
  }

  f32x4 oacc[4] = {};
  float m_r[4], l_r[4];
#pragma unroll
  for (int j = 0; j < 4; j++) { m_r[j] = -3e38f; l_r[j] = 0.f; }

  // staging maps
  const int ksr = tid >> 2, ksc = (tid & 3) * 16;  // K: 64 rows x 4 col-chunks of 16
  const int vr = tid & 63, vc = (tid >> 6) * 16;   // V: 64 rows x 4 col-chunks (per wave)

  // prologue: load tile 0
  short8 kA0 = ld8(KgH + (size_t)ksr * 1536 + ksc);
  short8 kA1 = ld8(KgH + (size_t)ksr * 1536 + ksc + 8);
  short8 kB0 = ld8(KgL + (size_t)ksr * 1536 + ksc);
  short8 kB1 = ld8(KgL + (size_t)ksr * 1536 + ksc + 8);
  short8 v0 = ld8(Vg + (size_t)vr * 1536 + vc);
  short8 v1 = ld8(Vg + (size_t)vr * 1536 + vc + 8);

  for (int kt = 0; kt < 2048; kt += 64) {
    __syncthreads();  // prior tile's LDS reads complete
    *(short8*)&Kh[ksr * SK + ksc] = kA0;
    *(short8*)&Kh[ksr * SK + ksc + 8] = kA1;
    *(short8*)&Kl[ksr * SK + ksc] = kB0;
    *(short8*)&Kl[ksr * SK + ksc + 8] = kB1;
#pragma unroll
    for (int i = 0; i < 8; i++) {
      Vt[(vc + i) * SV + vr] = (u16)v0[i];
      Vt[(vc + 8 + i) * SV + vr] = (u16)v1[i];
    }
    __syncthreads();  // tile ready
    if (kt + 64 < 2048) {  // issue next tile's loads; latency hides under compute
      int nk = kt + 64;
      kA0 = ld8(KgH + (size_t)(nk + ksr) * 1536 + ksc);
      kA1 = ld8(KgH + (size_t)(nk + ksr) * 1536 + ksc + 8);
      kB0 = ld8(KgL + (size_t)(nk + ksr) * 1536 + ksc);
      kB1 = ld8(KgL + (size_t)(nk + ksr) * 1536 + ksc + 8);
      v0 = ld8(Vg + (size_t)(nk + vr) * 1536 + vc);
      v1 = ld8(Vg + (size_t)(nk + vr) * 1536 + vc + 8);
    }
    // ---- QK^T (split bf16: hi*hi + hi*lo + lo*hi) ----
    f32x4 s[4] = {};
#pragma unroll
    for (int f = 0; f < 4; f++)
#pragma unroll
      for (int ks = 0; ks < 2; ks++) {
        short8 bh = *(const short8*)&Kh[(f * 16 + r16) * SK + ks * 32 + g * 8];
        short8 bl = *(const short8*)&Kl[(f * 16 + r16) * SK + ks * 32 + g * 8];
        s[f] = mfma16(qh[ks], bh, s[f]);
        s[f] = mfma16(qh[ks], bl, s[f]);
        s[f] = mfma16(qlo[ks], bh, s[f]);
      }
    // ---- online softmax (rows = g*4+j, cols = f*16+r16) ----
    float scl[4];
#pragma unroll
    for (int j = 0; j < 4; j++) {
      float a0 = s[0][j] * 0.125f, a1 = s[1][j] * 0.125f;
      float a2 = s[2][j] * 0.125f, a3 = s[3][j] * 0.125f;
      float vm = fmaxf(fmaxf(a0, a1), fmaxf(a2, a3));
      vm = fmaxf(vm, __shfl_xor(vm, 1));
      vm = fmaxf(vm, __shfl_xor(vm, 2));
      vm = fmaxf(vm, __shfl_xor(vm, 4));
      vm = fmaxf(vm, __shfl_xor(vm, 8));
      float mn = fmaxf(m_r[j], vm);
      float e0 = __expf(a0 - mn), e1 = __expf(a1 - mn);
      float e2 = __expf(a2 - mn), e3 = __expf(a3 - mn);
      float rs = (e0 + e1) + (e2 + e3);
      rs += __shfl_xor(rs, 1);
      rs += __shfl_xor(rs, 2);
      rs += __shfl_xor(rs, 4);
      rs += __shfl_xor(rs, 8);
      scl[j] = __expf(m_r[j] - mn);
      m_r[j] = mn;
      l_r[j] = l_r[j] * scl[j] + rs;
      int pr = (g * 4 + j) * SP + r16;
      Pl[w][pr] = e0;
      Pl[w][pr + 16] = e1;
      Pl[w][pr + 32] = e2;
      Pl[w][pr + 48] = e3;
    }
#pragma unroll
    for (int dt = 0; dt < 4; dt++)
#pragma unroll
      for (int j = 0; j < 4; j++) oacc[dt][j] *= scl[j];
    // ---- P@V ----
#pragma unroll
    for (int ks = 0; ks < 2; ks++) {
      f32x4 p0 = *(const f32x4*)&Pl[w][r16 * SP + ks * 32 + g * 8];
      f32x4 p1 = *(const f32x4*)&Pl[w][r16 * SP + ks * 32 + g * 8 + 4];
      short8 pa;
#pragma unroll
      for (int i = 0; i < 4; i++) {
        pa[i] = (short)f2bf(p0[i]);
        pa[i + 4] = (short)f2bf(p1[i]);
      }
#pragma unroll
      for (int dt = 0; dt < 4; dt++) {
        short8 vb = *(const short8*)&Vt[(dt * 16 + r16) * SV + ks * 32 + g * 8];
        oacc[dt] = mfma16(pa, vb, oacc[dt]);
      }
    }
  }
  // epilogue
#pragma unroll
  for (int dt = 0; dt < 4; dt++)
#pragma unroll
    for (int j = 0; j < 4; j++) {
      int row = b * 2048 + qb + w * 16 + g * 4 + j;
      int col = h * 64 + dt * 16 + r16;
      o[(size_t)row * 512 + col] = f2bf(oacc[dt][j] / l_r[j]);
    }
}

// ---------------- launcher ----------------
extern "C" void kernel_launch(void* const* d_in, const int* in_sizes, int n_in,
                              void* d_out, int out_size, void* d_ws, size_t ws_size,
                              hipStream_t stream) {
  const float* z = (const float*)d_in[0];
  const float* head_w = (const float*)d_in[1];
  const float* w_o = (const float*)d_in[2];
  const float* ln_w = (const float*)d_in[3];
  const float* ln_b = (const float*)d_in[4];
  const float* w1 = (const float*)d_in[5];
  const float* b1 = (const float*)d_in[6];
  const float* w2 = (const float*)d_in[7];
  const float* b2 = (const float*)d_in[8];
  float* out = (float*)d_out;

  size_t off = 0;
  auto alc = [&](size_t n) {
    void* p = (char*)d_ws + off;
    off += (n + 255) & ~(size_t)255;
    return p;
  };
  u16* x_hi = (u16*)alc((size_t)4096 * 512 * 2);
  u16* x_lo = (u16*)alc((size_t)4096 * 512 * 2);
  u16* wqh = (u16*)alc((size_t)1536 * 512 * 2);
  u16* wql = (u16*)alc((size_t)1536 * 512 * 2);
  u16* woT = (u16*)alc((size_t)512 * 512 * 2);
  u16* w1T = (u16*)alc((size_t)128 * 512 * 2);
  u16* w2T = (u16*)alc((size_t)512 * 128 * 2);
  u16* qkvh = (u16*)alc((size_t)4096 * 1536 * 2);
  u16* qkvl = (u16*)alc((size_t)4096 * 1536 * 2);
  u16* ob = (u16*)alc((size_t)4096 * 512 * 2);
  float* z2 = (float*)alc((size_t)4096 * 512 * 4);
  u16* tb = (u16*)alc((size_t)4096 * 128 * 2);

  // fused weight prep (1,179,648 work items)
  prep_all<<<4608, 256, 0, stream>>>(head_w, w_o, w1, w2, wqh, wql, woT, w1T, w2T);

  // LN1: z -> x hi/lo
  ln_kernel<<<1024, 256, 0, stream>>>(z, ln_w, ln_b, x_hi, x_lo);

  // QKV projection (split for precision): qkv = x @ Wqkv
  gemm_bf16<true, 4><<<dim3(32, 12), 256, 0, stream>>>(x_hi, x_lo, wqh, wql, nullptr, nullptr,
                                                       qkvh, qkvl, nullptr, 4096, 1536, 512);

  // flash attention (512 blocks -> 2 blocks/CU)
  attn_kernel<<<dim3(32, 16), 256, 0, stream>>>(qkvh, qkvl, ob);

  // z2 = o @ w_o + z
  gemm_bf16<false, 1><<<dim3(32, 4), 256, 0, stream>>>(ob, nullptr, woT, nullptr, z, nullptr,
                                                       nullptr, nullptr, z2, 4096, 512, 512);

  // LN2: z2 -> y hi/lo (reuse x buffers)
  ln_kernel<<<1024, 256, 0, stream>>>(z2, ln_w, ln_b, x_hi, x_lo);

  // t = y @ w1 + b1
  gemm_bf16<false, 2><<<dim3(32, 1), 256, 0, stream>>>(x_hi, nullptr, w1T, nullptr, nullptr, b1,
                                                       tb, nullptr, nullptr, 4096, 128, 512);

  // out = gelu(t @ w2 + b2) + z2
  gemm_bf16<false, 3><<<dim3(32, 4), 256, 0, stream>>>(tb, nullptr, w2T, nullptr, z2, b2,
                                                       nullptr, nullptr, out, 4096, 512, 128);
}

// Round 4
// 144.527 us; speedup vs baseline: 1.7056x; 1.3587x over previous
//
#include <hip/hip_runtime.h>
#include <hip/hip_bf16.h>

typedef unsigned short u16;
typedef __attribute__((ext_vector_type(8))) short short8;
typedef __attribute__((ext_vector_type(8))) __bf16 bf16x8;
typedef __attribute__((ext_vector_type(4))) float f32x4;

#define DEV static __device__ __forceinline__

DEV float bf2f(u16 u) { unsigned v = ((unsigned)u) << 16; float f; __builtin_memcpy(&f, &v, 4); return f; }
DEV u16 f2bf(float f) {
  unsigned u; __builtin_memcpy(&u, &f, 4);
  unsigned lsb = (u >> 16) & 1;
  u += 0x7fffu + lsb;  // RNE
  return (u16)(u >> 16);
}
DEV u16 tbf(float f) {  // truncate (for P in [0,1]: bias ~2^-10, harmless)
  unsigned u; __builtin_memcpy(&u, &f, 4);
  return (u16)(u >> 16);
}
DEV float exp2fast(float x) { return __builtin_amdgcn_exp2f(x); }  // v_exp_f32
DEV f32x4 mfma16(short8 a, short8 b, f32x4 c) {
  return __builtin_amdgcn_mfma_f32_16x16x32_bf16(
      __builtin_bit_cast(bf16x8, a), __builtin_bit_cast(bf16x8, b), c, 0, 0, 0);
}
DEV short8 ld8(const u16* p) { return *(const short8*)p; }

// ---------------- fused weight prep ----------------
// head_w (H,D,3DH): e<64 -> Q col h*64+e; e<128 -> K col 512+h*64+(e-64) (both hi+lo);
//                   e>=128 -> V col 1024+h*64+(e-128) (hi only). W_T stored [n][d].
__global__ void prep_all(const float* __restrict__ hw, const float* __restrict__ wo,
                         const float* __restrict__ w1, const float* __restrict__ w2,
                         u16* __restrict__ wqh, u16* __restrict__ wql,
                         u16* __restrict__ woT, u16* __restrict__ w1T, u16* __restrict__ w2T) {
  int idx = blockIdx.x * 256 + threadIdx.x;
  if (idx < 786432) {  // 8*512*192
    int e = idx % 192;
    int d = (idx / 192) % 512;
    int h = idx / (192 * 512);
    float v = hw[idx];
    int n = (e < 64) ? (h * 64 + e) : (e < 128) ? (512 + h * 64 + e - 64) : (1024 + h * 64 + e - 128);
    size_t oi = (size_t)n * 512 + d;
    u16 hh = f2bf(v);
    wqh[oi] = hh;
    if (e < 128) wql[oi] = f2bf(v - bf2f(hh));
  } else if (idx < 786432 + 262144) {
    int i = idx - 786432;  // wo: K=512, N=512
    int n = i % 512, k = i / 512;
    woT[(size_t)n * 512 + k] = f2bf(wo[i]);
  } else if (idx < 786432 + 262144 + 65536) {
    int i = idx - (786432 + 262144);  // w1: K=512, N=128
    int n = i % 128, k = i / 128;
    w1T[(size_t)n * 512 + k] = f2bf(w1[i]);
  } else if (idx < 786432 + 262144 + 131072) {
    int i = idx - (786432 + 262144 + 65536);  // w2: K=128, N=512
    int n = i % 512, k = i / 512;
    w2T[(size_t)n * 128 + k] = f2bf(w2[i]);
  }
}

// ---------------- LayerNorm: f32 (rows x 512) -> bf16 hi/lo ----------------
__global__ __launch_bounds__(256) void ln_kernel(const float* __restrict__ in,
                                                 const float* __restrict__ w,
                                                 const float* __restrict__ bb,
                                                 u16* __restrict__ hi, u16* __restrict__ lo) {
  const int wv = threadIdx.x >> 6, lane = threadIdx.x & 63;
  const int row = blockIdx.x * 4 + wv;
  const float4* r = (const float4*)(in + (size_t)row * 512);
  float4 a0 = r[lane * 2], a1 = r[lane * 2 + 1];
  float s = a0.x + a0.y + a0.z + a0.w + a1.x + a1.y + a1.z + a1.w;
  float ss = a0.x * a0.x + a0.y * a0.y + a0.z * a0.z + a0.w * a0.w +
             a1.x * a1.x + a1.y * a1.y + a1.z * a1.z + a1.w * a1.w;
#pragma unroll
  for (int m = 1; m < 64; m <<= 1) { s += __shfl_xor(s, m); ss += __shfl_xor(ss, m); }
  float mu = s * (1.f / 512.f);
  float var = ss * (1.f / 512.f) - mu * mu;
  float rstd = rsqrtf(var + 1e-5f);
  const float4* wp = (const float4*)w + lane * 2;
  const float4* bp = (const float4*)bb + lane * 2;
  float4 w0 = wp[0], w1v = wp[1], b0 = bp[0], b1v = bp[1];
  float xv[8] = {a0.x, a0.y, a0.z, a0.w, a1.x, a1.y, a1.z, a1.w};
  float wv8[8] = {w0.x, w0.y, w0.z, w0.w, w1v.x, w1v.y, w1v.z, w1v.w};
  float bv8[8] = {b0.x, b0.y, b0.z, b0.w, b1v.x, b1v.y, b1v.z, b1v.w};
  short8 oh, ol;
#pragma unroll
  for (int i = 0; i < 8; i++) {
    float v = (xv[i] - mu) * rstd * wv8[i] + bv8[i];
    u16 hh = f2bf(v);
    oh[i] = (short)hh;
    ol[i] = (short)f2bf(v - bf2f(hh));
  }
  *(short8*)(hi + (size_t)row * 512 + lane * 8) = oh;
  *(short8*)(lo + (size_t)row * 512 + lane * 8) = ol;
}

// ---------------- QKV GEMM: BM=128, BN=64, grid (32,24) ----------------
// blockIdx.y<16: split path (Q,K cols, 3 MFMA, hi+lo out). else: plain V (1 MFMA, hi out).
__global__ __launch_bounds__(256) void gemm_qkv(const u16* __restrict__ Ah, const u16* __restrict__ Alo,
                                                const u16* __restrict__ Bh, const u16* __restrict__ Blo,
                                                u16* __restrict__ outh, u16* __restrict__ outl) {
  __shared__ __align__(16) u16 As[128][40], Asl[128][40], Bs[64][40], Bsl[64][40];
  const int tid = threadIdx.x, lane = tid & 63, wv = tid >> 6;
  const int wm = wv >> 1, wn = wv & 1, g = lane >> 4, r16 = lane & 15;
  const int bm = blockIdx.x * 128, bn = blockIdx.y * 64;
  const bool split = blockIdx.y < 16;
  short8 sA[2], sAl[2], sB, sBl;
  auto ldtile = [&](int kt) {
#pragma unroll
    for (int c = 0; c < 2; c++) {
      int ch = c * 256 + tid;
      sA[c] = ld8(Ah + (size_t)(bm + (ch >> 2)) * 512 + kt + (ch & 3) * 8);
      if (split) sAl[c] = ld8(Alo + (size_t)(bm + (ch >> 2)) * 512 + kt + (ch & 3) * 8);
    }
    sB = ld8(Bh + (size_t)(bn + (tid >> 2)) * 512 + kt + (tid & 3) * 8);
    if (split) sBl = ld8(Blo + (size_t)(bn + (tid >> 2)) * 512 + kt + (tid & 3) * 8);
  };
  f32x4 acc[4][2] = {};
  ldtile(0);
  for (int kt = 0; kt < 512; kt += 32) {
    __syncthreads();
#pragma unroll
    for (int c = 0; c < 2; c++) {
      int ch = c * 256 + tid;
      *(short8*)&As[ch >> 2][(ch & 3) * 8] = sA[c];
      if (split) *(short8*)&Asl[ch >> 2][(ch & 3) * 8] = sAl[c];
    }
    *(short8*)&Bs[tid >> 2][(tid & 3) * 8] = sB;
    if (split) *(short8*)&Bsl[tid >> 2][(tid & 3) * 8] = sBl;
    __syncthreads();
    if (kt + 32 < 512) ldtile(kt + 32);
    short8 af[4], bf_[2], afl[4], bfl[2];
#pragma unroll
    for (int mi = 0; mi < 4; mi++) af[mi] = *(const short8*)&As[wm * 64 + mi * 16 + r16][g * 8];
#pragma unroll
    for (int ni = 0; ni < 2; ni++) bf_[ni] = *(const short8*)&Bs[wn * 32 + ni * 16 + r16][g * 8];
    if (split) {
#pragma unroll
      for (int mi = 0; mi < 4; mi++) afl[mi] = *(const short8*)&Asl[wm * 64 + mi * 16 + r16][g * 8];
#pragma unroll
      for (int ni = 0; ni < 2; ni++) bfl[ni] = *(const short8*)&Bsl[wn * 32 + ni * 16 + r16][g * 8];
    }
#pragma unroll
    for (int mi = 0; mi < 4; mi++)
#pragma unroll
      for (int ni = 0; ni < 2; ni++) {
        acc[mi][ni] = mfma16(af[mi], bf_[ni], acc[mi][ni]);
        if (split) {
          acc[mi][ni] = mfma16(af[mi], bfl[ni], acc[mi][ni]);
          acc[mi][ni] = mfma16(afl[mi], bf_[ni], acc[mi][ni]);
        }
      }
  }
#pragma unroll
  for (int mi = 0; mi < 4; mi++)
#pragma unroll
    for (int ni = 0; ni < 2; ni++) {
      int col = bn + wn * 32 + ni * 16 + r16;
      int row0 = bm + wm * 64 + mi * 16 + g * 4;
#pragma unroll
      for (int j = 0; j < 4; j++) {
        size_t oi = (size_t)(row0 + j) * 1536 + col;
        float v = acc[mi][ni][j];
        u16 hh = f2bf(v);
        outh[oi] = hh;
        if (split) outl[oi] = f2bf(v - bf2f(hh));
      }
    }
}

// ---------------- generic GEMM: BM=32*MF, BN=32*NF; EPI 1:+res f32, 2:+bias bf16, 3:+bias gelu +res f32 ----------------
template <int MF, int NF, int EPI>
__global__ __launch_bounds__(256) void gemm_g(const u16* __restrict__ A, const u16* __restrict__ BT,
                                              const float* __restrict__ res, const float* __restrict__ bias,
                                              u16* __restrict__ outb, float* __restrict__ outf,
                                              int N, int K) {
  constexpr int BM = 32 * MF, BN = 32 * NF;
  constexpr int CA = (BM * 4 + 255) / 256, CB = (BN * 4 + 255) / 256;
  __shared__ __align__(16) u16 As[BM][40], Bs[BN][40];
  const int tid = threadIdx.x, lane = tid & 63, wv = tid >> 6;
  const int wm = wv >> 1, wn = wv & 1, g = lane >> 4, r16 = lane & 15;
  const int bm = blockIdx.x * BM, bn = blockIdx.y * BN;
  short8 sA[CA], sB[CB];
  auto ldtile = [&](int kt) {
#pragma unroll
    for (int c = 0; c < CA; c++) {
      int ch = c * 256 + tid;
      if (ch < BM * 4) sA[c] = ld8(A + (size_t)(bm + (ch >> 2)) * K + kt + (ch & 3) * 8);
    }
#pragma unroll
    for (int c = 0; c < CB; c++) {
      int ch = c * 256 + tid;
      if (ch < BN * 4) sB[c] = ld8(BT + (size_t)(bn + (ch >> 2)) * K + kt + (ch & 3) * 8);
    }
  };
  f32x4 acc[MF][NF] = {};
  ldtile(0);
  for (int kt = 0; kt < K; kt += 32) {
    __syncthreads();
#pragma unroll
    for (int c = 0; c < CA; c++) {
      int ch = c * 256 + tid;
      if (ch < BM * 4) *(short8*)&As[ch >> 2][(ch & 3) * 8] = sA[c];
    }
#pragma unroll
    for (int c = 0; c < CB; c++) {
      int ch = c * 256 + tid;
      if (ch < BN * 4) *(short8*)&Bs[ch >> 2][(ch & 3) * 8] = sB[c];
    }
    __syncthreads();
    if (kt + 32 < K) ldtile(kt + 32);
    short8 af[MF], bf_[NF];
#pragma unroll
    for (int mi = 0; mi < MF; mi++) af[mi] = *(const short8*)&As[wm * 16 * MF + mi * 16 + r16][g * 8];
#pragma unroll
    for (int ni = 0; ni < NF; ni++) bf_[ni] = *(const short8*)&Bs[wn * 16 * NF + ni * 16 + r16][g * 8];
#pragma unroll
    for (int mi = 0; mi < MF; mi++)
#pragma unroll
      for (int ni = 0; ni < NF; ni++) acc[mi][ni] = mfma16(af[mi], bf_[ni], acc[mi][ni]);
  }
#pragma unroll
  for (int mi = 0; mi < MF; mi++)
#pragma unroll
    for (int ni = 0; ni < NF; ni++) {
      int col = bn + wn * 16 * NF + ni * 16 + r16;
      int row0 = bm + wm * 16 * MF + mi * 16 + g * 4;
#pragma unroll
      for (int j = 0; j < 4; j++) {
        size_t oi = (size_t)(row0 + j) * N + col;
        float v = acc[mi][ni][j];
        if (EPI == 1) {
          outf[oi] = v + res[oi];
        } else if (EPI == 2) {
          outb[oi] = f2bf(v + bias[col]);
        } else {
          float u = v + bias[col];
          float gl = 0.5f * u * (1.0f + erff(u * 0.70710678118f));
          outf[oi] = gl + res[oi];
        }
      }
    }
}

// ---------------- flash attention v3: QBLK=64 (4 waves x 16 rows), KVBLK=128 ----------------
__global__ __launch_bounds__(256) void attn_kernel(const u16* __restrict__ qkv_hi,
                                                   const u16* __restrict__ qkv_lo,
                                                   u16* __restrict__ o) {
  constexpr int SK = 72, SV = 136, SP = 136;
  __shared__ __align__(16) u16 Kh[128 * SK], Kl[128 * SK], Vt[64 * SV];
  __shared__ __align__(16) u16 Pl[4][16 * SP];
  const int tid = threadIdx.x, lane = tid & 63, w = tid >> 6;
  const int g = lane >> 4, r16 = lane & 15;
  const int qb = blockIdx.x * 64;
  const int b = blockIdx.y >> 3, h = blockIdx.y & 7;
  const size_t bbase = (size_t)b * 2048 * 1536;
  const u16* Qh = qkv_hi + bbase + h * 64;
  const u16* Ql = qkv_lo + bbase + h * 64;
  const u16* KgH = qkv_hi + bbase + 512 + h * 64;
  const u16* KgL = qkv_lo + bbase + 512 + h * 64;
  const u16* Vg = qkv_hi + bbase + 1024 + h * 64;

  const int qrow = qb + w * 16 + r16;
  short8 qh[2], qlo[2];
#pragma unroll
  for (int ks = 0; ks < 2; ks++) {
    qh[ks] = ld8(Qh + (size_t)qrow * 1536 + ks * 32 + g * 8);
    qlo[ks] = ld8(Ql + (size_t)qrow * 1536 + ks * 32 + g * 8);
  }

  f32x4 oacc[4] = {};
  float m_r[4], l_r[4];
#pragma unroll
  for (int j = 0; j < 4; j++) { m_r[j] = -3e38f; l_r[j] = 0.f; }

  short8 kA[4], kB[4], vS[4];
  auto ldkv = [&](int kt) {
#pragma unroll
    for (int c = 0; c < 4; c++) {
      int ch = c * 256 + tid;
      int kr = ch >> 3, kc = (ch & 7) * 8;
      kA[c] = ld8(KgH + (size_t)(kt + kr) * 1536 + kc);
      kB[c] = ld8(KgL + (size_t)(kt + kr) * 1536 + kc);
    }
#pragma unroll
    for (int c = 0; c < 2; c++)
#pragma unroll
      for (int c2 = 0; c2 < 2; c2++)
        vS[c * 2 + c2] = ld8(Vg + (size_t)(kt + c * 64 + lane) * 1536 + w * 16 + c2 * 8);
  };
  ldkv(0);

  for (int kt = 0; kt < 2048; kt += 128) {
    __syncthreads();
#pragma unroll
    for (int c = 0; c < 4; c++) {
      int ch = c * 256 + tid;
      int kr = ch >> 3, kc = (ch & 7) * 8;
      *(short8*)&Kh[kr * SK + kc] = kA[c];
      *(short8*)&Kl[kr * SK + kc] = kB[c];
    }
#pragma unroll
    for (int c = 0; c < 2; c++)
#pragma unroll
      for (int c2 = 0; c2 < 2; c2++)
#pragma unroll
        for (int i = 0; i < 8; i++)
          Vt[(w * 16 + c2 * 8 + i) * SV + c * 64 + lane] = (u16)vS[c * 2 + c2][i];
    __syncthreads();
    if (kt + 128 < 2048) ldkv(kt + 128);
    // ---- QK^T (split: hi*hi + hi*lo + lo*hi) ----
    f32x4 s[8];
#pragma unroll
    for (int f = 0; f < 8; f++) {
      s[f] = f32x4{0.f, 0.f, 0.f, 0.f};
#pragma unroll
      for (int ks = 0; ks < 2; ks++) {
        short8 bh = *(const short8*)&Kh[(f * 16 + r16) * SK + ks * 32 + g * 8];
        short8 bl = *(const short8*)&Kl[(f * 16 + r16) * SK + ks * 32 + g * 8];
        s[f] = mfma16(qh[ks], bh, s[f]);
        s[f] = mfma16(qh[ks], bl, s[f]);
        s[f] = mfma16(qlo[ks], bh, s[f]);
      }
    }
    // ---- online softmax in log2 domain (v_exp_f32 computes 2^x natively) ----
    constexpr float SCL2 = 0.125f * 1.44269504f;
    float scl[4];
#pragma unroll
    for (int j = 0; j < 4; j++) {
      float a[8];
#pragma unroll
      for (int f = 0; f < 8; f++) a[f] = s[f][j] * SCL2;
      float vm = fmaxf(fmaxf(fmaxf(a[0], a[1]), fmaxf(a[2], a[3])),
                       fmaxf(fmaxf(a[4], a[5]), fmaxf(a[6], a[7])));
      vm = fmaxf(vm, __shfl_xor(vm, 1));
      vm = fmaxf(vm, __shfl_xor(vm, 2));
      vm = fmaxf(vm, __shfl_xor(vm, 4));
      vm = fmaxf(vm, __shfl_xor(vm, 8));
      float mn = fmaxf(m_r[j], vm);
      float rs = 0.f;
      int pr = (g * 4 + j) * SP + r16;
#pragma unroll
      for (int f = 0; f < 8; f++) {
        float e = exp2fast(a[f] - mn);
        rs += e;
        Pl[w][pr + f * 16] = tbf(e);
      }
      rs += __shfl_xor(rs, 1);
      rs += __shfl_xor(rs, 2);
      rs += __shfl_xor(rs, 4);
      rs += __shfl_xor(rs, 8);
      scl[j] = exp2fast(m_r[j] - mn);
      m_r[j] = mn;
      l_r[j] = l_r[j] * scl[j] + rs;
    }
#pragma unroll
    for (int dt = 0; dt < 4; dt++)
#pragma unroll
      for (int j = 0; j < 4; j++) oacc[dt][j] *= scl[j];
    // ---- P@V ----
#pragma unroll
    for (int ks = 0; ks < 4; ks++) {
      short8 pa = *(const short8*)&Pl[w][r16 * SP + ks * 32 + g * 8];
#pragma unroll
      for (int dt = 0; dt < 4; dt++) {
        short8 vb = *(const short8*)&Vt[(dt * 16 + r16) * SV + ks * 32 + g * 8];
        oacc[dt] = mfma16(pa, vb, oacc[dt]);
      }
    }
  }
  float il[4];
#pragma unroll
  for (int j = 0; j < 4; j++) il[j] = 1.f / l_r[j];
#pragma unroll
  for (int dt = 0; dt < 4; dt++)
#pragma unroll
    for (int j = 0; j < 4; j++) {
      int row = b * 2048 + qb + w * 16 + g * 4 + j;
      int col = h * 64 + dt * 16 + r16;
      o[(size_t)row * 512 + col] = f2bf(oacc[dt][j] * il[j]);
    }
}

// ---------------- launcher ----------------
extern "C" void kernel_launch(void* const* d_in, const int* in_sizes, int n_in,
                              void* d_out, int out_size, void* d_ws, size_t ws_size,
                              hipStream_t stream) {
  const float* z = (const float*)d_in[0];
  const float* head_w = (const float*)d_in[1];
  const float* w_o = (const float*)d_in[2];
  const float* ln_w = (const float*)d_in[3];
  const float* ln_b = (const float*)d_in[4];
  const float* w1 = (const float*)d_in[5];
  const float* b1 = (const float*)d_in[6];
  const float* w2 = (const float*)d_in[7];
  const float* b2 = (const float*)d_in[8];
  float* out = (float*)d_out;

  size_t off = 0;
  auto alc = [&](size_t n) {
    void* p = (char*)d_ws + off;
    off += (n + 255) & ~(size_t)255;
    return p;
  };
  u16* x_hi = (u16*)alc((size_t)4096 * 512 * 2);
  u16* x_lo = (u16*)alc((size_t)4096 * 512 * 2);
  u16* wqh = (u16*)alc((size_t)1536 * 512 * 2);
  u16* wql = (u16*)alc((size_t)1536 * 512 * 2);
  u16* woT = (u16*)alc((size_t)512 * 512 * 2);
  u16* w1T = (u16*)alc((size_t)128 * 512 * 2);
  u16* w2T = (u16*)alc((size_t)512 * 128 * 2);
  u16* qkvh = (u16*)alc((size_t)4096 * 1536 * 2);
  u16* qkvl = (u16*)alc((size_t)4096 * 1536 * 2);
  u16* ob = (u16*)alc((size_t)4096 * 512 * 2);
  float* z2 = (float*)alc((size_t)4096 * 512 * 4);
  u16* tb = (u16*)alc((size_t)4096 * 128 * 2);

  prep_all<<<4608, 256, 0, stream>>>(head_w, w_o, w1, w2, wqh, wql, woT, w1T, w2T);

  // LN1: z -> x hi/lo
  ln_kernel<<<1024, 256, 0, stream>>>(z, ln_w, ln_b, x_hi, x_lo);

  // QKV projection: split path for Q,K cols; plain for V cols. 768 blocks = 3/CU.
  gemm_qkv<<<dim3(32, 24), 256, 0, stream>>>(x_hi, x_lo, wqh, wql, qkvh, qkvl);

  // flash attention (512 blocks, KVBLK=128)
  attn_kernel<<<dim3(32, 16), 256, 0, stream>>>(qkvh, qkvl, ob);

  // z2 = o @ w_o + z   (64x64 tiles, 512 blocks)
  gemm_g<2, 2, 1><<<dim3(64, 8), 256, 0, stream>>>(ob, woT, z, nullptr, nullptr, z2, 512, 512);

  // LN2: z2 -> y hi/lo (reuse x buffers)
  ln_kernel<<<1024, 256, 0, stream>>>(z2, ln_w, ln_b, x_hi, x_lo);

  // t = y @ w1 + b1   (32x64 tiles, 256 blocks)
  gemm_g<1, 2, 2><<<dim3(128, 2), 256, 0, stream>>>(x_hi, w1T, nullptr, b1, tb, nullptr, 128, 512);

  // out = gelu(t @ w2 + b2) + z2   (64x64 tiles, 512 blocks)
  gemm_g<2, 2, 3><<<dim3(64, 8), 256, 0, stream>>>(tb, w2T, z2, b2, nullptr, out, 512, 128);
}